// Round 6
// baseline (382.368 us; speedup 1.0000x reference)
//
#include <hip/hip_runtime.h>
#include <hip/hip_bf16.h>

// B=4, T=1024, D=1024, E=8, H=2048. Tokens N = B*T = 4096.
#define NTOK 4096
#define DDIM 1024
#define HDIM 2048
#define NEXP 8

typedef __attribute__((ext_vector_type(4))) float f32x4;
typedef __attribute__((ext_vector_type(8))) short bf16x8;
typedef __attribute__((ext_vector_type(8))) unsigned short us8;

__device__ __forceinline__ unsigned short f2bf(float f) {
    unsigned u = __float_as_uint(f);
    return (unsigned short)((u + 0x7fffu + ((u >> 16) & 1u)) >> 16);   // RNE
}

__device__ __forceinline__ void gload16(const void* g, void* l) {
    __builtin_amdgcn_global_load_lds((const __attribute__((address_space(1))) void*)g,
                                     (__attribute__((address_space(3))) void*)l, 16, 0, 0);
}

// ------- prep: X fp32 -> bf16, fused with gate logits (fp64) + argmax -------
__global__ __launch_bounds__(256) void xg_kernel(
        const float* __restrict__ x, const float* __restrict__ gw,
        unsigned short* __restrict__ xb, int* __restrict__ sel) {
    const int t = blockIdx.x, tid = threadIdx.x, lane = tid & 63, w = tid >> 6;
    const float4 v = *reinterpret_cast<const float4*>(x + (size_t)t * DDIM + tid * 4);
    ushort4 o = { f2bf(v.x), f2bf(v.y), f2bf(v.z), f2bf(v.w) };
    *reinterpret_cast<ushort4*>(xb + (size_t)t * DDIM + tid * 4) = o;

    double acc[NEXP];
    #pragma unroll
    for (int e = 0; e < NEXP; ++e) {
        const float4 g = *reinterpret_cast<const float4*>(gw + (size_t)e * DDIM + tid * 4);
        acc[e] = (double)v.x * g.x + (double)v.y * g.y + (double)v.z * g.z + (double)v.w * g.w;
    }
    __shared__ double red[4][NEXP];
    #pragma unroll
    for (int e = 0; e < NEXP; ++e) {
        double a = acc[e];
        #pragma unroll
        for (int off = 32; off; off >>= 1) a += __shfl_down(a, off);
        if (lane == 0) red[w][e] = a;
    }
    __syncthreads();
    if (tid == 0) {
        int best = 0; double bv = -1e300;
        #pragma unroll
        for (int e = 0; e < NEXP; ++e) {
            double s = red[0][e] + red[1][e] + red[2][e] + red[3][e];
            if (s > bv) { bv = s; best = e; }
        }
        sel[t] = best;
    }
}

__global__ void scatter_kernel(const int* __restrict__ sel, int* __restrict__ cnt,
                               int* __restrict__ perm) {
    int t = blockIdx.x * blockDim.x + threadIdx.x;
    if (t < NTOK) {
        int e = sel[t];
        int p = atomicAdd(&cnt[e], 1);
        perm[e * NTOK + p] = t;
    }
}

// ---- prep: transpose-cast weight bank into MFMA B-fragment order ----
// src fp32 [e][R(=k)][C(=n)] -> dst bf16 fragment chunks:
//   flat = ((e*NB + nblk)*KS + kslice)*512 + l*8 + j
//   where lane l = lg*16+li holds B[n=nblk*16+li][k=kslice*32+lg*8+j].
// interleave=1 (gate/up): nblk = ((c0>>4)+q)*2 + qsel.
__global__ __launch_bounds__(256) void fcast(const float* __restrict__ src,
        unsigned short* __restrict__ dst, int R, int C, int NB, int KS,
        int interleave, int qsel, long long estride) {
    __shared__ unsigned short tile[64][72];   // [n_loc][k_loc], pad 72 (16B-align ok)
    const int e = blockIdx.z, r0 = blockIdx.y * 64, c0 = blockIdx.x * 64;
    const float* s = src + ((size_t)e * R + r0) * C + c0;
    const int t = threadIdx.x;
    const int rd = t >> 2;
    #pragma unroll
    for (int j = 0; j < 4; ++j) {
        int c4 = (t & 3) * 4 + j;
        float4 v = *reinterpret_cast<const float4*>(s + (size_t)rd * C + c4 * 4);
        tile[c4 * 4 + 0][rd] = f2bf(v.x);
        tile[c4 * 4 + 1][rd] = f2bf(v.y);
        tile[c4 * 4 + 2][rd] = f2bf(v.z);
        tile[c4 * 4 + 3][rd] = f2bf(v.w);
    }
    __syncthreads();
    const int q = t >> 6, l = t & 63, li = l & 15, lg = l >> 4;
    const int nblk = interleave ? (((c0 >> 4) + q) * 2 + qsel) : ((c0 >> 4) + q);
    #pragma unroll
    for (int kf2 = 0; kf2 < 2; ++kf2) {
        const int ks = (r0 >> 5) + kf2;
        us8 v = *reinterpret_cast<const us8*>(&tile[q * 16 + li][kf2 * 32 + lg * 8]);
        *reinterpret_cast<us8*>(dst + ((size_t)e * estride) +
            (((size_t)nblk * KS + ks) << 9) + l * 8) = v;
    }
}

// ---------------- stage A: h = silu(X G) * (X U) ----------------
// BM=128 tok, BN=128 interleaved cols, BK=64. 4 waves (2x2), wave tile 64x64.
// A: LDS (gload_lds w=16, XOR-swizzle, 2-phase dbuf). B: direct global->reg.
__global__ __launch_bounds__(256, 3) void stage_a(
        const unsigned short* __restrict__ xb, const unsigned short* __restrict__ wa,
        const int* __restrict__ cnt, const int* __restrict__ perm,
        unsigned short* __restrict__ hws) {
    const int e = blockIdx.z;
    const int bx = blockIdx.x;            // 0..31  (interleaved n, 128 each)
    const int m0 = blockIdx.y * 128;
    const int count = cnt[e];
    if (m0 >= count) return;
    const int* pl = perm + e * NTOK;

    __shared__ unsigned short __attribute__((aligned(16))) As[2][128 * 64];

    const int tid = threadIdx.x, lane = tid & 63, w = tid >> 6;
    const int wr = w >> 1, wc = w & 1, li = lane & 15, lg = lane >> 4;
    const int sb = lane & 7, r8 = lane >> 3;
    const int srcswz = (sb ^ r8) * 8;

    const unsigned short* pA[4];
    #pragma unroll
    for (int i = 0; i < 4; ++i) {
        int row = i * 32 + w * 8 + r8;
        int tr = m0 + row; if (tr >= count) tr = count - 1;
        pA[i] = xb + (size_t)pl[tr] * DDIM + srcswz;
    }
    // B fragment base: nblk = bx*8 + wc*4 + ni, KS=32 kslices, 1KB chunks.
    const unsigned short* bp = wa + (((size_t)e * 256 + bx * 8 + wc * 4) << 5 << 9)
                               + (size_t)lane * 8;

    f32x4 acc[4][4];
    #pragma unroll
    for (int i = 0; i < 4; ++i)
        #pragma unroll
        for (int j = 0; j < 4; ++j) acc[i][j] = (f32x4){0.f, 0.f, 0.f, 0.f};

    #pragma unroll
    for (int i = 0; i < 4; ++i) gload16(pA[i], &As[0][(i * 256 + w * 64) * 8]);
    asm volatile("s_waitcnt vmcnt(0)" ::: "memory");
    __syncthreads();

    int cur = 0;
    const int NT = DDIM / 64;
    for (int t = 0; t < NT; ++t) {
        if (t + 1 < NT) {
            const int k0 = (t + 1) * 64;
            #pragma unroll
            for (int i = 0; i < 4; ++i) gload16(pA[i] + k0, &As[cur ^ 1][(i * 256 + w * 64) * 8]);
        }
        #pragma unroll
        for (int kf = 0; kf < 2; ++kf) {
            const int kb = kf * 4 + lg;
            bf16x8 a[4], b[4];
            #pragma unroll
            for (int ni = 0; ni < 4; ++ni)
                b[ni] = *reinterpret_cast<const bf16x8*>(bp + (((size_t)(ni * 32 + t * 2 + kf)) << 9));
            #pragma unroll
            for (int mi = 0; mi < 4; ++mi) {
                int r = wr * 64 + mi * 16 + li;
                a[mi] = *reinterpret_cast<const bf16x8*>(&As[cur][r * 64 + ((kb ^ (li & 7)) << 3)]);
            }
            #pragma unroll
            for (int mi = 0; mi < 4; ++mi)
                #pragma unroll
                for (int ni = 0; ni < 4; ++ni)
                    acc[mi][ni] = __builtin_amdgcn_mfma_f32_16x16x32_bf16(a[mi], b[ni], acc[mi][ni], 0, 0, 0);
        }
        if (t + 1 < NT) {
            asm volatile("s_waitcnt vmcnt(0)" ::: "memory");
            __syncthreads();
            cur ^= 1;
        }
    }
    // epilogue: acc[mi][2p+q] -> h = bx*64 + wc*32 + p*16 + li
    const int hbase = bx * 64 + wc * 32 + li;
    #pragma unroll
    for (int mi = 0; mi < 4; ++mi) {
        #pragma unroll
        for (int r = 0; r < 4; ++r) {
            int row = m0 + wr * 64 + mi * 16 + lg * 4 + r;
            if (row < count) {
                int tok = pl[row];
                #pragma unroll
                for (int p = 0; p < 2; ++p) {
                    float a = acc[mi][p * 2 + 0][r];
                    float u = acc[mi][p * 2 + 1][r];
                    float h = (a / (1.f + __expf(-a))) * u;
                    hws[(size_t)tok * HDIM + hbase + p * 16] = f2bf(h);
                }
            }
        }
    }
}

// ---------------- stage B: out = H Down ----------------
// BM=128 tok, BN=128 d-cols, K=2048 (KS=64). Same structure as stage A.
__global__ __launch_bounds__(256, 3) void stage_b(
        const unsigned short* __restrict__ hws, const unsigned short* __restrict__ wb,
        const int* __restrict__ cnt, const int* __restrict__ perm,
        float* __restrict__ out) {
    const int e = blockIdx.z;
    const int bx = blockIdx.x;            // 0..7
    const int m0 = blockIdx.y * 128;
    const int count = cnt[e];
    if (m0 >= count) return;
    const int* pl = perm + e * NTOK;

    __shared__ unsigned short __attribute__((aligned(16))) As[2][128 * 64];

    const int tid = threadIdx.x, lane = tid & 63, w = tid >> 6;
    const int wr = w >> 1, wc = w & 1, li = lane & 15, lg = lane >> 4;
    const int sb = lane & 7, r8 = lane >> 3;
    const int srcswz = (sb ^ r8) * 8;

    const unsigned short* pA[4];
    #pragma unroll
    for (int i = 0; i < 4; ++i) {
        int row = i * 32 + w * 8 + r8;
        int tr = m0 + row; if (tr >= count) tr = count - 1;
        pA[i] = hws + (size_t)pl[tr] * HDIM + srcswz;
    }
    const unsigned short* bp = wb + (((size_t)e * 64 + bx * 8 + wc * 4) * 64 << 9)
                               + (size_t)lane * 8;

    f32x4 acc[4][4];
    #pragma unroll
    for (int i = 0; i < 4; ++i)
        #pragma unroll
        for (int j = 0; j < 4; ++j) acc[i][j] = (f32x4){0.f, 0.f, 0.f, 0.f};

    #pragma unroll
    for (int i = 0; i < 4; ++i) gload16(pA[i], &As[0][(i * 256 + w * 64) * 8]);
    asm volatile("s_waitcnt vmcnt(0)" ::: "memory");
    __syncthreads();

    int cur = 0;
    const int NT = HDIM / 64;
    for (int t = 0; t < NT; ++t) {
        if (t + 1 < NT) {
            const int k0 = (t + 1) * 64;
            #pragma unroll
            for (int i = 0; i < 4; ++i) gload16(pA[i] + k0, &As[cur ^ 1][(i * 256 + w * 64) * 8]);
        }
        #pragma unroll
        for (int kf = 0; kf < 2; ++kf) {
            const int kb = kf * 4 + lg;
            bf16x8 a[4], b[4];
            #pragma unroll
            for (int ni = 0; ni < 4; ++ni)
                b[ni] = *reinterpret_cast<const bf16x8*>(bp + (((size_t)(ni * 64 + t * 2 + kf)) << 9));
            #pragma unroll
            for (int mi = 0; mi < 4; ++mi) {
                int r = wr * 64 + mi * 16 + li;
                a[mi] = *reinterpret_cast<const bf16x8*>(&As[cur][r * 64 + ((kb ^ (li & 7)) << 3)]);
            }
            #pragma unroll
            for (int mi = 0; mi < 4; ++mi)
                #pragma unroll
                for (int ni = 0; ni < 4; ++ni)
                    acc[mi][ni] = __builtin_amdgcn_mfma_f32_16x16x32_bf16(a[mi], b[ni], acc[mi][ni], 0, 0, 0);
        }
        if (t + 1 < NT) {
            asm volatile("s_waitcnt vmcnt(0)" ::: "memory");
            __syncthreads();
            cur ^= 1;
        }
    }
    const int cbase = bx * 128 + wc * 64 + li;
    #pragma unroll
    for (int mi = 0; mi < 4; ++mi) {
        #pragma unroll
        for (int r = 0; r < 4; ++r) {
            int row = m0 + wr * 64 + mi * 16 + lg * 4 + r;
            if (row < count) {
                int tok = pl[row];
                #pragma unroll
                for (int ni = 0; ni < 4; ++ni)
                    out[(size_t)tok * DDIM + cbase + ni * 16] = acc[mi][ni][r];
            }
        }
    }
}

// ---------------- launch ----------------
extern "C" void kernel_launch(void* const* d_in, const int* in_sizes, int n_in,
                              void* d_out, int out_size, void* d_ws, size_t ws_size,
                              hipStream_t stream) {
    const float* x  = (const float*)d_in[0];
    const float* gw = (const float*)d_in[1];
    const float* gb = (const float*)d_in[2];
    const float* ub = (const float*)d_in[3];
    const float* db = (const float*)d_in[4];
    float* out = (float*)d_out;

    char* ws = (char*)d_ws;
    // wbank: WA frag-order (64 MB); reused as WB (32 MB) after stage_a.
    unsigned short* wbank = (unsigned short*)(ws);
    unsigned short* hws   = (unsigned short*)(ws + 67108864);            // 16 MB
    unsigned short* xbf   = (unsigned short*)(ws + 67108864 + 16777216); // 8 MB
    char* misc = ws + 67108864 + 16777216 + 8388608;
    int* cnt  = (int*)(misc);
    int* sel  = (int*)(misc + 256);
    int* perm = (int*)(misc + 256 + 16384);

    hipMemsetAsync(cnt, 0, 256, stream);
    xg_kernel<<<NTOK, 256, 0, stream>>>(x, gw, xbf, sel);
    // WA: gate (qsel 0) + up (qsel 1), interleaved nblk. NB=256, KS=32.
    fcast<<<dim3(HDIM / 64, DDIM / 64, NEXP), 256, 0, stream>>>(
        gb, wbank, DDIM, HDIM, 256, 32, 1, 0, (long long)256 * 32 * 512);
    fcast<<<dim3(HDIM / 64, DDIM / 64, NEXP), 256, 0, stream>>>(
        ub, wbank, DDIM, HDIM, 256, 32, 1, 1, (long long)256 * 32 * 512);
    scatter_kernel<<<NTOK / 256, 256, 0, stream>>>(sel, cnt, perm);
    stage_a<<<dim3(2 * HDIM / 128, NTOK / 128, NEXP), 256, 0, stream>>>(
        xbf, wbank, cnt, perm, hws);
    // WB: down_bank, plain nblk. NB=64, KS=64. Overwrites WA (done with it).
    fcast<<<dim3(DDIM / 64, HDIM / 64, NEXP), 256, 0, stream>>>(
        db, wbank, HDIM, DDIM, 64, 64, 0, 0, (long long)64 * 64 * 512);
    stage_b<<<dim3(DDIM / 128, NTOK / 128, NEXP), 256, 0, stream>>>(
        hws, wbank, cnt, perm, out);
}